// Round 1
// baseline (257.376 us; speedup 1.0000x reference)
//
#include <hip/hip_runtime.h>

// Quantizers (QKeras semantics, round-half-to-even == jnp.round == rintf w/ RNE)
__device__ __forceinline__ float qbits8(float x) {
    float q = rintf(x * 128.0f);
    q = fminf(fmaxf(q, -128.0f), 127.0f);
    return q * (1.0f / 128.0f);
}
__device__ __forceinline__ float qrelu8(float x) {
    float q = rintf(x * 256.0f);
    q = fminf(fmaxf(q, 0.0f), 255.0f);
    return q * (1.0f / 256.0f);
}

// ws layout (floats):
//  [0)     qw1T [64][48]   (3072)
//  [3072)  qb1  [64]
//  [3136)  qw2T [32][64]   (2048)
//  [5184)  qb2  [32]
//  [5216)  qw3T [32][32]   (1024)
//  [6240)  qb3  [32]
//  [6272)  woutT[5][32]    (160)
//  [6432)  bout [5]
// total 6437 floats = 25.7 KB

__global__ void prep_weights(const float* __restrict__ w1, const float* __restrict__ b1,
                             const float* __restrict__ w2, const float* __restrict__ b2,
                             const float* __restrict__ w3, const float* __restrict__ b3,
                             const float* __restrict__ wout, const float* __restrict__ bout,
                             float* __restrict__ ws) {
    int t = threadIdx.x;
    for (int idx = t; idx < 48 * 64; idx += 256) {      // w1 is [48][64]
        int i = idx / 64, j = idx % 64;
        ws[0 + j * 48 + i] = qbits8(w1[idx]);
    }
    for (int idx = t; idx < 64; idx += 256) ws[3072 + idx] = qbits8(b1[idx]);
    for (int idx = t; idx < 64 * 32; idx += 256) {      // w2 is [64][32]
        int i = idx / 32, j = idx % 32;
        ws[3136 + j * 64 + i] = qbits8(w2[idx]);
    }
    for (int idx = t; idx < 32; idx += 256) ws[5184 + idx] = qbits8(b2[idx]);
    for (int idx = t; idx < 32 * 32; idx += 256) {      // w3 is [32][32]
        int i = idx / 32, j = idx % 32;
        ws[5216 + j * 32 + i] = qbits8(w3[idx]);
    }
    for (int idx = t; idx < 32; idx += 256) ws[6240 + idx] = qbits8(b3[idx]);
    for (int idx = t; idx < 5 * 32; idx += 256) {       // wout is [32][5], NOT quantized
        int i = idx / 5, j = idx % 5;
        ws[6272 + j * 32 + i] = wout[idx];
    }
    for (int idx = t; idx < 5; idx += 256) ws[6432 + idx] = bout[idx];
}

__global__ __launch_bounds__(256) void mlp_fwd(const float* __restrict__ x,
                                               const float* __restrict__ wq,
                                               float* __restrict__ out, int nrows) {
    int row = blockIdx.x * 256 + threadIdx.x;
    if (row >= nrows) return;

    const float* xr = x + (long)row * 48;
    float xv[48];
    #pragma unroll
    for (int q = 0; q < 12; ++q) {
        float4 t = reinterpret_cast<const float4*>(xr)[q];
        xv[q * 4 + 0] = t.x; xv[q * 4 + 1] = t.y;
        xv[q * 4 + 2] = t.z; xv[q * 4 + 3] = t.w;
    }

    float h1[64];
    #pragma unroll
    for (int j = 0; j < 64; ++j) {
        float a = wq[3072 + j];
        #pragma unroll
        for (int i = 0; i < 48; ++i) a += xv[i] * wq[j * 48 + i];
        h1[j] = qrelu8(a);
    }

    float h2[32];
    #pragma unroll
    for (int j = 0; j < 32; ++j) {
        float a = wq[5184 + j];
        #pragma unroll
        for (int k = 0; k < 64; ++k) a += h1[k] * wq[3136 + j * 64 + k];
        h2[j] = qrelu8(a);
    }

    float h3[32];
    #pragma unroll
    for (int j = 0; j < 32; ++j) {
        float a = wq[6240 + j];
        #pragma unroll
        for (int k = 0; k < 32; ++k) a += h2[k] * wq[5216 + j * 32 + k];
        h3[j] = qrelu8(a);
    }

    float o[5];
    #pragma unroll
    for (int m = 0; m < 5; ++m) {
        float a = wq[6432 + m];
        #pragma unroll
        for (int k = 0; k < 32; ++k) a += h3[k] * wq[6272 + m * 32 + k];
        o[m] = a;
    }
    float* orow = out + (long)row * 5;
    orow[0] = o[0]; orow[1] = o[1]; orow[2] = o[2]; orow[3] = o[3]; orow[4] = o[4];
}

extern "C" void kernel_launch(void* const* d_in, const int* in_sizes, int n_in,
                              void* d_out, int out_size, void* d_ws, size_t ws_size,
                              hipStream_t stream) {
    const float* x    = (const float*)d_in[0];
    const float* w1   = (const float*)d_in[1];
    const float* b1   = (const float*)d_in[2];
    const float* w2   = (const float*)d_in[3];
    const float* b2   = (const float*)d_in[4];
    const float* w3   = (const float*)d_in[5];
    const float* b3   = (const float*)d_in[6];
    const float* wout = (const float*)d_in[7];
    const float* bout = (const float*)d_in[8];
    float* ws  = (float*)d_ws;
    float* out = (float*)d_out;

    int B = in_sizes[0] / 48;

    prep_weights<<<1, 256, 0, stream>>>(w1, b1, w2, b2, w3, b3, wout, bout, ws);

    int blocks = (B + 255) / 256;
    mlp_fwd<<<blocks, 256, 0, stream>>>(x, ws, out, B);
}

// Round 3
// 61.020 us; speedup vs baseline: 4.2179x; 4.2179x over previous
//
#include <hip/hip_runtime.h>

typedef short  short8 __attribute__((ext_vector_type(8)));
typedef float  f32x4  __attribute__((ext_vector_type(4)));
typedef unsigned int u32;
typedef unsigned long long u64;
typedef unsigned short u16;

// ---------- helpers ----------
__device__ __forceinline__ u32 f2bf(float v) {              // fp32 -> bf16 bits (RNE)
    u32 u = __float_as_uint(v);
    return (u + 0x7FFFu + ((u >> 16) & 1u)) >> 16;
}
__device__ __forceinline__ float qround128(float w) {       // round(w*128) clip [-128,127]
    float q = rintf(w * 128.0f);
    return fminf(fmaxf(q, -128.0f), 127.0f);
}
// qrelu in integer domain: k = clamp(rndne(acc),0,255). k<=255 is exact in bf16
// and its fp32 low 16 bits are zero -> bf16 bits = f32 bits >> 16 exactly.
// Packs 4 consecutive FEATURES (D regs = out-feats 4g+0..3) of one batch row.
__device__ __forceinline__ u64 qrelu_pack4(f32x4 a) {
    u32 u0 = __float_as_uint(fminf(fmaxf(rintf(a[0]), 0.f), 255.f));
    u32 u1 = __float_as_uint(fminf(fmaxf(rintf(a[1]), 0.f), 255.f));
    u32 u2 = __float_as_uint(fminf(fmaxf(rintf(a[2]), 0.f), 255.f));
    u32 u3 = __float_as_uint(fminf(fmaxf(rintf(a[3]), 0.f), 255.f));
    u32 lo = (u0 >> 16) | (u1 & 0xFFFF0000u);
    u32 hi = (u2 >> 16) | (u3 & 0xFFFF0000u);
    return (u64)lo | ((u64)hi << 32);
}
union FragU { short8 s; u32 u[4]; };
__device__ __forceinline__ f32x4 mfma16(short8 a, short8 b, f32x4 c) {
    return __builtin_amdgcn_mfma_f32_16x16x32_bf16(a, b, c, 0, 0, 0);
}

// ---------- ws layout ----------
// shorts [0..8192): 16 A-fragment blocks (weights TRANSPOSED: A[row=out-feat][k=in-feat]),
// 512 shorts each, element = blk*512 + lane*8 + j; lane: r=lane&15 (out-feat), g=lane>>4,
// k = (ks*32) + 8g + j.
//   blk 0..7 : L1  [mt(4)][ks(2)]  val = 2*qround128(w1[k][mt*16+r])   (0 if k>=48)
//   blk 8..11: L2  [mt(2)][ks(2)]  val = qround128(w2[k][mt*16+r])/128
//   blk 12,13: L3  [mt(2)]         val = qround128(w3[k][mt*16+r])/128
//   blk 14   : Wout hi             val = bf16(wout[k][r]/256)  (r>=5 -> 0)
//   blk 15   : Wout lo residual
// floats at short-offset 8192: [0,64) 2*qr128(b1); [64,96) 2*qr(b2); [96,128) 2*qr(b3);
//   [128,144) bout padded with zeros.

__global__ void prep(const float* __restrict__ w1, const float* __restrict__ b1,
                     const float* __restrict__ w2, const float* __restrict__ b2,
                     const float* __restrict__ w3, const float* __restrict__ b3,
                     const float* __restrict__ wo, const float* __restrict__ bo,
                     u16* __restrict__ wsh) {
    int t = threadIdx.x;
    for (int idx = t; idx < 16 * 512; idx += 256) {
        int blk = idx >> 9, e = idx & 511;
        int l = e >> 3, j = e & 7;
        int r  = l & 15;                 // out-feature within 16-block (A row)
        int kk = ((l >> 4) << 3) + j;    // k within a 32-step
        float val = 0.f;
        if (blk < 8) {
            int mt = blk >> 1, ks = blk & 1;
            int k = ks * 32 + kk, fo = mt * 16 + r;
            if (k < 48) val = 2.0f * qround128(w1[k * 64 + fo]);
        } else if (blk < 12) {
            int bi = blk - 8, mt = bi >> 1, ks = bi & 1;
            int k = ks * 32 + kk, fo = mt * 16 + r;
            val = qround128(w2[k * 32 + fo]) * (1.0f / 128.0f);
        } else if (blk < 14) {
            int mt = blk - 12;
            val = qround128(w3[kk * 32 + mt * 16 + r]) * (1.0f / 128.0f);
        } else {
            float wv = (r < 5) ? wo[kk * 5 + r] * (1.0f / 256.0f) : 0.f;
            u32 hb = f2bf(wv);
            if (blk == 14) { wsh[idx] = (u16)hb; continue; }
            val = wv - __uint_as_float(hb << 16);
        }
        wsh[idx] = (u16)f2bf(val);
    }
    float* wsf = (float*)(wsh + 8192);
    for (int i = t; i < 64; i += 256) wsf[i]       = 2.0f * qround128(b1[i]);
    for (int i = t; i < 32; i += 256) wsf[64 + i]  = 2.0f * qround128(b2[i]);
    for (int i = t; i < 32; i += 256) wsf[96 + i]  = 2.0f * qround128(b3[i]);
    for (int i = t; i < 16; i += 256) wsf[128 + i] = (i < 5) ? bo[i] : 0.f;
}

// ---------- main kernel ----------
// Transposed dataflow: D = A*B with A = W^T (weights), B = H^T (activations).
// B-frag: lane(c,g) elem j = H[batch-row c][feat 8g+j]  -> plain ds_read_b128.
// D:      lane(c,g) reg r  = out-feat 4g+r of batch-row c -> plain ds_write_b64.
// LDS per wave: H1 @0 (16 rows x 80 shorts), H2 @1280, H3 @2560 (stride 160B).

__global__ __launch_bounds__(256) void mlp_mfma(const float* __restrict__ x,
                                                const u16* __restrict__ wsh,
                                                float* __restrict__ out, int ntiles) {
    __shared__ __align__(16) u16 smem[4][3840];
    const int tid = threadIdx.x;
    const int wid = tid >> 6, lane = tid & 63;
    const int c = lane & 15, g = lane >> 4;

    // resident weight A-fragments (16 x 4 VGPR = 64 VGPR)
    short8 wf[16];
    const short8* wv = (const short8*)wsh;
    #pragma unroll
    for (int i = 0; i < 16; ++i) wf[i] = wv[i * 64 + lane];

    // biases: acc reg r <-> out-feat mt*16 + 4g + r  -> float4 at [mt*16 + 4g]
    const float* wsf = (const float*)(wsh + 8192);
    f32x4 b1q[4], b2q[2], b3q[2], boq;
    #pragma unroll
    for (int i = 0; i < 4; ++i) b1q[i] = *(const f32x4*)(wsf + i * 16 + 4 * g);
    #pragma unroll
    for (int i = 0; i < 2; ++i) b2q[i] = *(const f32x4*)(wsf + 64 + i * 16 + 4 * g);
    #pragma unroll
    for (int i = 0; i < 2; ++i) b3q[i] = *(const f32x4*)(wsf + 96 + i * 16 + 4 * g);
    boq = *(const f32x4*)(wsf + 128 + 4 * g);

    u16* H = &smem[wid][0];

    const int gw = blockIdx.x * 4 + wid;
    const int nw = gridDim.x * 4;

    for (int t0 = gw; t0 < ntiles; t0 += nw) {
        // ---- x tile load: lane(c,g) -> batch-row c, k = 8g..8g+7 (+32 for g<2)
        const float* xl = x + (size_t)t0 * 768 + (c * 48 + g * 8);
        float4 xa = *(const float4*)(xl);
        float4 xb = *(const float4*)(xl + 4);
        float4 xc = {0.f, 0.f, 0.f, 0.f}, xd = {0.f, 0.f, 0.f, 0.f};
        if (g < 2) { xc = *(const float4*)(xl + 32); xd = *(const float4*)(xl + 36); }

        // ---- hi/lo bf16 split of x (B-operand fragments)
        float v0[8] = {xa.x, xa.y, xa.z, xa.w, xb.x, xb.y, xb.z, xb.w};
        float v1[8] = {xc.x, xc.y, xc.z, xc.w, xd.x, xd.y, xd.z, xd.w};
        FragU bh0, bl0, bh1, bl1;
        #pragma unroll
        for (int p = 0; p < 4; ++p) {
            u32 a0 = f2bf(v0[2 * p]), a1 = f2bf(v0[2 * p + 1]);
            float r0 = v0[2 * p] - __uint_as_float(a0 << 16);
            float r1 = v0[2 * p + 1] - __uint_as_float(a1 << 16);
            bh0.u[p] = a0 | (a1 << 16);
            bl0.u[p] = f2bf(r0) | (f2bf(r1) << 16);
            u32 c0 = f2bf(v1[2 * p]), c1 = f2bf(v1[2 * p + 1]);
            float s0 = v1[2 * p] - __uint_as_float(c0 << 16);
            float s1 = v1[2 * p + 1] - __uint_as_float(c1 << 16);
            bh1.u[p] = c0 | (c1 << 16);
            bl1.u[p] = f2bf(s0) | (f2bf(s1) << 16);
        }

        // ---- layer 1: acc = 256*preact (weights pre-scaled x2, x int-coded x256 later)
        #pragma unroll
        for (int mt = 0; mt < 4; ++mt) {
            f32x4 a = b1q[mt];
            a = mfma16(wf[mt * 2 + 0], bh0.s, a);
            a = mfma16(wf[mt * 2 + 1], bh1.s, a);
            a = mfma16(wf[mt * 2 + 0], bl0.s, a);
            a = mfma16(wf[mt * 2 + 1], bl1.s, a);
            *(u64*)(H + c * 80 + mt * 16 + 4 * g) = qrelu_pack4(a);
        }

        // ---- layer 2 (K=64): B-frags = plain b128 reads of H1 row c
        short8 p0 = *(const short8*)(H + c * 80 + 8 * g);
        short8 p1 = *(const short8*)(H + c * 80 + 32 + 8 * g);
        #pragma unroll
        for (int mt = 0; mt < 2; ++mt) {
            f32x4 a = b2q[mt];
            a = mfma16(wf[8 + mt * 2 + 0], p0, a);
            a = mfma16(wf[8 + mt * 2 + 1], p1, a);
            *(u64*)(H + 1280 + c * 80 + mt * 16 + 4 * g) = qrelu_pack4(a);
        }

        // ---- layer 3 (K=32)
        short8 p2 = *(const short8*)(H + 1280 + c * 80 + 8 * g);
        #pragma unroll
        for (int mt = 0; mt < 2; ++mt) {
            f32x4 a = b3q[mt];
            a = mfma16(wf[12 + mt], p2, a);
            *(u64*)(H + 2560 + c * 80 + mt * 16 + 4 * g) = qrelu_pack4(a);
        }

        // ---- output layer: wout/256 hi + lo, acc init = bout
        short8 p3 = *(const short8*)(H + 2560 + c * 80 + 8 * g);
        f32x4 ao = boq;
        ao = mfma16(wf[14], p3, ao);
        ao = mfma16(wf[15], p3, ao);

        // D: lane(c,g) reg r = logit 4g+r of batch-row c; only logits 0..4 exist
        float* orow = out + (size_t)t0 * 80 + c * 5;
        if (g == 0) {
            orow[0] = ao[0]; orow[1] = ao[1]; orow[2] = ao[2]; orow[3] = ao[3];
        } else if (g == 1) {
            orow[4] = ao[0];
        }
    }
}

extern "C" void kernel_launch(void* const* d_in, const int* in_sizes, int n_in,
                              void* d_out, int out_size, void* d_ws, size_t ws_size,
                              hipStream_t stream) {
    const float* x  = (const float*)d_in[0];
    const float* w1 = (const float*)d_in[1];
    const float* b1 = (const float*)d_in[2];
    const float* w2 = (const float*)d_in[3];
    const float* b2 = (const float*)d_in[4];
    const float* w3 = (const float*)d_in[5];
    const float* b3 = (const float*)d_in[6];
    const float* wo = (const float*)d_in[7];
    const float* bo = (const float*)d_in[8];
    float* out = (float*)d_out;

    int B = in_sizes[0] / 48;
    int ntiles = B / 16;                       // 1e6 -> 62500 exactly

    prep<<<1, 256, 0, stream>>>(w1, b1, w2, b2, w3, b3, wo, bo, (u16*)d_ws);

    int blocks = (ntiles + 3) / 4;
    if (blocks > 2048) blocks = 2048;
    mlp_mfma<<<blocks, 256, 0, stream>>>(x, (const u16*)d_ws, out, ntiles);
}

// Round 4
// 60.391 us; speedup vs baseline: 4.2618x; 1.0104x over previous
//
#include <hip/hip_runtime.h>
#include <hip/hip_bf16.h>

typedef short  short8 __attribute__((ext_vector_type(8)));
typedef float  f32x4  __attribute__((ext_vector_type(4)));
typedef unsigned int u32;
typedef unsigned long long u64;
typedef unsigned short u16;

// ---------- helpers ----------
__device__ __forceinline__ u32 f2bf(float v) {              // fp32 -> bf16 bits (RNE), prep only
    u32 u = __float_as_uint(v);
    return (u + 0x7FFFu + ((u >> 16) & 1u)) >> 16;
}
__device__ __forceinline__ float qround128(float w) {       // round(w*128) clip [-128,127]
    float q = rintf(w * 128.0f);
    return fminf(fmaxf(q, -128.0f), 127.0f);
}
// packed RNE f32x2 -> bf16x2 (v_cvt_pk_bf16_f32); low half = a, high half = b
__device__ __forceinline__ u32 cvtpk(float a, float b) {
    __hip_bfloat162 h = __float22bfloat162_rn(make_float2(a, b));
    union { __hip_bfloat162 h; u32 u; } cv; cv.h = h; return cv.u;
}
// qrelu in integer domain: k = clamp(rndne(acc),0,255); k<=255 exact in bf16, so
// cvt_pk packing is exact. Packs 4 consecutive features of one batch row.
__device__ __forceinline__ u64 qrelu_pack4(f32x4 a) {
    float q0 = fminf(fmaxf(rintf(a[0]), 0.f), 255.f);
    float q1 = fminf(fmaxf(rintf(a[1]), 0.f), 255.f);
    float q2 = fminf(fmaxf(rintf(a[2]), 0.f), 255.f);
    float q3 = fminf(fmaxf(rintf(a[3]), 0.f), 255.f);
    return (u64)cvtpk(q0, q1) | ((u64)cvtpk(q2, q3) << 32);
}
union FragU { short8 s; u32 u[4]; };
__device__ __forceinline__ f32x4 mfma16(short8 a, short8 b, f32x4 c) {
    return __builtin_amdgcn_mfma_f32_16x16x32_bf16(a, b, c, 0, 0, 0);
}

// ---------- ws layout ----------
// shorts [0..8192): 16 A-fragment blocks (weights transposed: A[out-feat][k]),
// 512 shorts each, element = blk*512 + lane*8 + j; lane: r=lane&15, g=lane>>4,
// k = ks*32 + 8g + j.
//   blk 0..7 : L1  [mt(4)][ks(2)]  val = 2*qround128(w1[k][mt*16+r])   (0 if k>=48)
//   blk 8..11: L2  [mt(2)][ks(2)]  val = qround128(w2[k][mt*16+r])/128
//   blk 12,13: L3  [mt(2)]         val = qround128(w3[k][mt*16+r])/128
//   blk 14   : Wout hi  bf16(wout[k][r]/256)  (r>=5 -> 0) ; blk 15: lo residual
// floats at short-offset 8192: [0,64) 2*qr128(b1); [64,96) 2*qr(b2); [96,128) 2*qr(b3);
//   [128,144) bout padded with zeros.

__global__ void prep(const float* __restrict__ w1, const float* __restrict__ b1,
                     const float* __restrict__ w2, const float* __restrict__ b2,
                     const float* __restrict__ w3, const float* __restrict__ b3,
                     const float* __restrict__ wo, const float* __restrict__ bo,
                     u16* __restrict__ wsh) {
    int t = threadIdx.x;
    for (int idx = t; idx < 16 * 512; idx += 256) {
        int blk = idx >> 9, e = idx & 511;
        int l = e >> 3, j = e & 7;
        int r  = l & 15;
        int kk = ((l >> 4) << 3) + j;
        float val = 0.f;
        if (blk < 8) {
            int mt = blk >> 1, ks = blk & 1;
            int k = ks * 32 + kk, fo = mt * 16 + r;
            if (k < 48) val = 2.0f * qround128(w1[k * 64 + fo]);
        } else if (blk < 12) {
            int bi = blk - 8, mt = bi >> 1, ks = bi & 1;
            int k = ks * 32 + kk, fo = mt * 16 + r;
            val = qround128(w2[k * 32 + fo]) * (1.0f / 128.0f);
        } else if (blk < 14) {
            int mt = blk - 12;
            val = qround128(w3[kk * 32 + mt * 16 + r]) * (1.0f / 128.0f);
        } else {
            float wv = (r < 5) ? wo[kk * 5 + r] * (1.0f / 256.0f) : 0.f;
            u32 hb = f2bf(wv);
            if (blk == 14) { wsh[idx] = (u16)hb; continue; }
            val = wv - __uint_as_float(hb << 16);
        }
        wsh[idx] = (u16)f2bf(val);
    }
    float* wsf = (float*)(wsh + 8192);
    for (int i = t; i < 64; i += 256) wsf[i]       = 2.0f * qround128(b1[i]);
    for (int i = t; i < 32; i += 256) wsf[64 + i]  = 2.0f * qround128(b2[i]);
    for (int i = t; i < 32; i += 256) wsf[96 + i]  = 2.0f * qround128(b3[i]);
    for (int i = t; i < 16; i += 256) wsf[128 + i] = (i < 5) ? bo[i] : 0.f;
}

// ---------- main kernel ----------
// Transposed dataflow: D = A*B, A = W^T (resident VGPR frags), B = H^T.
// B-frag: lane(c,g) elem j = H[row c][feat 8g+j] -> plain ds_read_b128.
// D:      lane(c,g) reg r  = out-feat 4g+r, row c -> plain ds_write_b64.
// Next-tile x loads are issued at the TOP of each iteration (software pipeline)
// so the ~900-cycle HBM latency hides under the current tile's compute chain.

__global__ __launch_bounds__(256, 2) void mlp_mfma(const float* __restrict__ x,
                                                   const u16* __restrict__ wsh,
                                                   float* __restrict__ out, int ntiles) {
    __shared__ __align__(16) u16 smem[4][3840];
    const int tid = threadIdx.x;
    const int wid = tid >> 6, lane = tid & 63;
    const int c = lane & 15, g = lane >> 4;

    // resident weight A-fragments (64 VGPR)
    short8 wf[16];
    const short8* wv = (const short8*)wsh;
    #pragma unroll
    for (int i = 0; i < 16; ++i) wf[i] = wv[i * 64 + lane];

    // biases: acc reg r <-> out-feat mt*16 + 4g + r
    const float* wsf = (const float*)(wsh + 8192);
    f32x4 b1q[4], b2q[2], b3q[2], boq;
    #pragma unroll
    for (int i = 0; i < 4; ++i) b1q[i] = *(const f32x4*)(wsf + i * 16 + 4 * g);
    #pragma unroll
    for (int i = 0; i < 2; ++i) b2q[i] = *(const f32x4*)(wsf + 64 + i * 16 + 4 * g);
    #pragma unroll
    for (int i = 0; i < 2; ++i) b3q[i] = *(const f32x4*)(wsf + 96 + i * 16 + 4 * g);
    boq = *(const f32x4*)(wsf + 128 + 4 * g);

    u16* H = &smem[wid][0];
    const int xoff = c * 48 + g * 8;

    const int gw = blockIdx.x * 4 + wid;
    const int nw = gridDim.x * 4;

    // prologue: load first tile
    const float* xl = x + (size_t)gw * 768 + xoff;
    float4 xa = *(const float4*)(xl);
    float4 xb = *(const float4*)(xl + 4);
    float4 xc = {0.f, 0.f, 0.f, 0.f}, xd = {0.f, 0.f, 0.f, 0.f};
    if (g < 2) { xc = *(const float4*)(xl + 32); xd = *(const float4*)(xl + 36); }

    for (int t0 = gw; t0 < ntiles; t0 += nw) {
        // ---- issue NEXT tile's loads first (hidden under this tile's compute)
        const int t1 = t0 + nw;
        const bool have = t1 < ntiles;
        float4 na, nb, nc, nd;
        if (have) {
            const float* nl = x + (size_t)t1 * 768 + xoff;
            na = *(const float4*)(nl);
            nb = *(const float4*)(nl + 4);
            if (g < 2) { nc = *(const float4*)(nl + 32); nd = *(const float4*)(nl + 36); }
        }

        // ---- hi/lo bf16 split of current x (B-operand fragments)
        float v0[8] = {xa.x, xa.y, xa.z, xa.w, xb.x, xb.y, xb.z, xb.w};
        float v1[8] = {xc.x, xc.y, xc.z, xc.w, xd.x, xd.y, xd.z, xd.w};
        FragU bh0, bl0, bh1, bl1;
        #pragma unroll
        for (int p = 0; p < 4; ++p) {
            u32 u = cvtpk(v0[2 * p], v0[2 * p + 1]);
            bh0.u[p] = u;
            float r0 = v0[2 * p]     - __uint_as_float(u << 16);
            float r1 = v0[2 * p + 1] - __uint_as_float(u & 0xFFFF0000u);
            bl0.u[p] = cvtpk(r0, r1);
            u32 w = cvtpk(v1[2 * p], v1[2 * p + 1]);
            bh1.u[p] = w;
            float s0 = v1[2 * p]     - __uint_as_float(w << 16);
            float s1 = v1[2 * p + 1] - __uint_as_float(w & 0xFFFF0000u);
            bl1.u[p] = cvtpk(s0, s1);
        }

        // ---- layer 1: acc = 256*preact
        #pragma unroll
        for (int mt = 0; mt < 4; ++mt) {
            f32x4 a = b1q[mt];
            a = mfma16(wf[mt * 2 + 0], bh0.s, a);
            a = mfma16(wf[mt * 2 + 1], bh1.s, a);
            a = mfma16(wf[mt * 2 + 0], bl0.s, a);
            a = mfma16(wf[mt * 2 + 1], bl1.s, a);
            *(u64*)(H + c * 80 + mt * 16 + 4 * g) = qrelu_pack4(a);
        }

        // ---- layer 2 (K=64)
        short8 p0 = *(const short8*)(H + c * 80 + 8 * g);
        short8 p1 = *(const short8*)(H + c * 80 + 32 + 8 * g);
        #pragma unroll
        for (int mt = 0; mt < 2; ++mt) {
            f32x4 a = b2q[mt];
            a = mfma16(wf[8 + mt * 2 + 0], p0, a);
            a = mfma16(wf[8 + mt * 2 + 1], p1, a);
            *(u64*)(H + 1280 + c * 80 + mt * 16 + 4 * g) = qrelu_pack4(a);
        }

        // ---- layer 3 (K=32)
        short8 p2 = *(const short8*)(H + 1280 + c * 80 + 8 * g);
        #pragma unroll
        for (int mt = 0; mt < 2; ++mt) {
            f32x4 a = b3q[mt];
            a = mfma16(wf[12 + mt], p2, a);
            *(u64*)(H + 2560 + c * 80 + mt * 16 + 4 * g) = qrelu_pack4(a);
        }

        // ---- output layer: wout/256 hi + lo, acc init = bout
        short8 p3 = *(const short8*)(H + 2560 + c * 80 + 8 * g);
        f32x4 ao = boq;
        ao = mfma16(wf[14], p3, ao);
        ao = mfma16(wf[15], p3, ao);

        float* orow = out + (size_t)t0 * 80 + c * 5;
        if (g == 0) {
            orow[0] = ao[0]; orow[1] = ao[1]; orow[2] = ao[2]; orow[3] = ao[3];
        } else if (g == 1) {
            orow[4] = ao[0];
        }

        // ---- rotate prefetched registers
        if (have) { xa = na; xb = nb; if (g < 2) { xc = nc; xd = nd; } }
    }
}

extern "C" void kernel_launch(void* const* d_in, const int* in_sizes, int n_in,
                              void* d_out, int out_size, void* d_ws, size_t ws_size,
                              hipStream_t stream) {
    const float* x  = (const float*)d_in[0];
    const float* w1 = (const float*)d_in[1];
    const float* b1 = (const float*)d_in[2];
    const float* w2 = (const float*)d_in[3];
    const float* b2 = (const float*)d_in[4];
    const float* w3 = (const float*)d_in[5];
    const float* b3 = (const float*)d_in[6];
    const float* wo = (const float*)d_in[7];
    const float* bo = (const float*)d_in[8];
    float* out = (float*)d_out;

    int B = in_sizes[0] / 48;
    int ntiles = B / 16;                       // 1e6 -> 62500 exactly

    prep<<<1, 256, 0, stream>>>(w1, b1, w2, b2, w3, b3, wo, bo, (u16*)d_ws);

    int blocks = (ntiles + 3) / 4;
    if (blocks > 2048) blocks = 2048;
    mlp_mfma<<<blocks, 256, 0, stream>>>(x, (const u16*)d_ws, out, ntiles);
}